// Round 7
// baseline (98.939 us; speedup 1.0000x reference)
//
#include <hip/hip_runtime.h>
#include <hip/hip_bf16.h>
#include <hip/hip_fp16.h>
#include <stdint.h>

// Problem constants
#define BATCH 256
#define NPOS 49
#define CCH 128
#define KWIN 7
#define HEADS 4
#define K2 49
#define HD 32
#define MROWS (BATCH * NPOS)         // 12544
#define QSCALE 0.17677669529663687f  // 32^-0.5

using short8 = __attribute__((ext_vector_type(8))) short;
using floatx4 = __attribute__((ext_vector_type(4))) float;

static __device__ inline short f2bf(float x) {
  uint32_t u = __float_as_uint(x);
  uint32_t r = (u + 0x7fffu + ((u >> 16) & 1u)) >> 16;
  return (short)r;
}

// ---------------------------------------------------------------------------
// bf16 MFMA GEMM (unchanged): C[M x N] = A[M x 128] @ W^T + bias
// ---------------------------------------------------------------------------
template <int MODE>
__global__ __launch_bounds__(256) void dwa_gemm(
    const float* __restrict__ A, const float* __restrict__ W0,
    const float* __restrict__ W1, const float* __restrict__ bias0,
    const float* __restrict__ bias1, float* __restrict__ out0,
    float* __restrict__ out1) {
  __shared__ short Abs[64][128];
  __shared__ short Bbs[64][128];
  const int tid = threadIdx.x;
  const int m0 = blockIdx.x * 64;
  const int n0 = blockIdx.y * 64;

#pragma unroll
  for (int p = 0; p < 4; ++p) {
    int c = tid + p * 256;
    int row = c >> 4;
    int slot = c & 15;
    const float* src = A + (size_t)(m0 + row) * 128 + slot * 8;
    float4 f0 = *(const float4*)(src);
    float4 f1 = *(const float4*)(src + 4);
    short8 pk;
    pk[0] = f2bf(f0.x); pk[1] = f2bf(f0.y); pk[2] = f2bf(f0.z); pk[3] = f2bf(f0.w);
    pk[4] = f2bf(f1.x); pk[5] = f2bf(f1.y); pk[6] = f2bf(f1.z); pk[7] = f2bf(f1.w);
    *(short8*)&Abs[row][(slot ^ (row & 7)) * 8] = pk;
  }
#pragma unroll
  for (int p = 0; p < 4; ++p) {
    int c = tid + p * 256;
    int row = c >> 4;
    int slot = c & 15;
    int colg = n0 + row;
    float4 f0 = make_float4(0.f, 0.f, 0.f, 0.f), f1 = f0;
    if (MODE == 1 || colg < 384) {
      const float* src = W0 + (size_t)colg * 128 + slot * 8;
      f0 = *(const float4*)(src);
      f1 = *(const float4*)(src + 4);
    } else if (colg < 776) {
      const float* src = W1 + (size_t)(colg - 384) * 128 + slot * 8;
      f0 = *(const float4*)(src);
      f1 = *(const float4*)(src + 4);
    }
    short8 pk;
    pk[0] = f2bf(f0.x); pk[1] = f2bf(f0.y); pk[2] = f2bf(f0.z); pk[3] = f2bf(f0.w);
    pk[4] = f2bf(f1.x); pk[5] = f2bf(f1.y); pk[6] = f2bf(f1.z); pk[7] = f2bf(f1.w);
    *(short8*)&Bbs[row][(slot ^ (row & 7)) * 8] = pk;
  }
  __syncthreads();

  const int lane = tid & 63;
  const int wv = tid >> 6;
  const int wrow = (wv >> 1) * 32;
  const int wcol = (wv & 1) * 32;
  const int lr = lane & 15;
  const int lg = lane >> 4;

  floatx4 acc[2][2];
#pragma unroll
  for (int i = 0; i < 2; ++i)
#pragma unroll
    for (int j = 0; j < 2; ++j) acc[i][j] = {0.f, 0.f, 0.f, 0.f};

#pragma unroll
  for (int ks = 0; ks < 4; ++ks) {
    short8 af[2], bf[2];
#pragma unroll
    for (int i = 0; i < 2; ++i) {
      int r = wrow + i * 16 + lr;
      int slot = (ks * 4 + lg) ^ (r & 7);
      af[i] = *(const short8*)&Abs[r][slot * 8];
    }
#pragma unroll
    for (int j = 0; j < 2; ++j) {
      int r = wcol + j * 16 + lr;
      int slot = (ks * 4 + lg) ^ (r & 7);
      bf[j] = *(const short8*)&Bbs[r][slot * 8];
    }
#pragma unroll
    for (int i = 0; i < 2; ++i)
#pragma unroll
      for (int j = 0; j < 2; ++j)
        acc[i][j] = __builtin_amdgcn_mfma_f32_16x16x32_bf16(af[i], bf[j],
                                                            acc[i][j], 0, 0, 0);
  }

#pragma unroll
  for (int i = 0; i < 2; ++i) {
#pragma unroll
    for (int reg = 0; reg < 4; ++reg) {
      int grow = m0 + wrow + i * 16 + lg * 4 + reg;
#pragma unroll
      for (int j = 0; j < 2; ++j) {
        int gcol = n0 + wcol + j * 16 + lr;
        float v = acc[i][j][reg];
        if (MODE == 1) {
          out0[(size_t)grow * 128 + gcol] = v + bias0[gcol];
        } else {
          if (gcol < 384) {
            float sc = (gcol < 128) ? QSCALE : 1.0f;
            out0[(size_t)grow * 384 + gcol] = (v + bias0[gcol]) * sc;
          } else if (gcol < 776) {
            out1[(size_t)grow * 392 + (gcol - 384)] = v + bias1[gcol - 384];
          }
        }
      }
    }
  }
}

// ---------------------------------------------------------------------------
// Deformable window attention: one block per (b,h), 512 threads = 8 waves
// (2x the waves of r6 -> 32 waves/CU when 4 blocks/CU co-resident).
// LDS ~19.1 KB: A2 fp32 UNIONed over dead q/k bf16 staging; S0 fp16; v fp16.
// Phases: stage(+off prefetch) | S0=q@k^T MFMA | zero A2 | scores+exp+
//         unnormalized scatter | out = (A2 @ v) / rowsum(A2).
// ---------------------------------------------------------------------------
__global__ __launch_bounds__(512, 8) void dwa_attn(
    const float* __restrict__ qkv_buf, const float* __restrict__ off_buf,
    const float* __restrict__ rpb, float* __restrict__ attn_out) {
  __shared__ __align__(16) char uA[10240];  // qbs+kbs (bf16), later A2 (fp32)
  __shared__ __align__(16) __half S0h[49 * 52 + 4];
  __shared__ __align__(16) __half vh[49 * 36];
  __shared__ float bias_s[49];

  short* qbs = (short*)uA;        // [64*40] bf16
  short* kbs = qbs + 64 * 40;     // [64*40] bf16
  float* A2 = (float*)uA;         // [49*52] fp32 (aliases qbs/kbs)

  const int bh = blockIdx.x;
  const int b = bh >> 2;
  const int h = bh & 3;
  const int tid = threadIdx.x;

  // ---- phase 1: stage q,k (bf16), v (fp16), bias ----
  if (tid < 256) {
    int r = tid >> 2;
    int c4 = tid & 3;
    if (r < 49) {
      const float* base = qkv_buf + (size_t)(b * 49 + r) * 384 + h * 32 + c4 * 8;
      float4 q0 = *(const float4*)(base);
      float4 q1 = *(const float4*)(base + 4);
      float4 k0 = *(const float4*)(base + 128);
      float4 k1 = *(const float4*)(base + 132);
      short8 qp, kp;
      qp[0] = f2bf(q0.x); qp[1] = f2bf(q0.y); qp[2] = f2bf(q0.z); qp[3] = f2bf(q0.w);
      qp[4] = f2bf(q1.x); qp[5] = f2bf(q1.y); qp[6] = f2bf(q1.z); qp[7] = f2bf(q1.w);
      kp[0] = f2bf(k0.x); kp[1] = f2bf(k0.y); kp[2] = f2bf(k0.z); kp[3] = f2bf(k0.w);
      kp[4] = f2bf(k1.x); kp[5] = f2bf(k1.y); kp[6] = f2bf(k1.z); kp[7] = f2bf(k1.w);
      *(short8*)&qbs[r * 40 + c4 * 8] = qp;
      *(short8*)&kbs[r * 40 + c4 * 8] = kp;
    } else {
      short8 zz = {0, 0, 0, 0, 0, 0, 0, 0};
      *(short8*)&qbs[r * 40 + c4 * 8] = zz;
      *(short8*)&kbs[r * 40 + c4 * 8] = zz;
    }
  } else {
    int t = tid - 256;
    const float* vbase = qkv_buf + (size_t)(b * 49) * 384 + 256 + h * 32;
    for (int i4 = t; i4 < 392; i4 += 256) {
      int n = i4 >> 3;
      int d4 = (i4 & 7) << 2;
      float4 vv = *(const float4*)(vbase + n * 384 + d4);
      *(__half2*)&vh[n * 36 + d4] = __floats2half2_rn(vv.x, vv.y);
      *(__half2*)&vh[n * 36 + d4 + 2] = __floats2half2_rn(vv.z, vv.w);
    }
    if (t < 49) {
      int k2 = t;
      int ky = k2 / 7, kx = k2 - ky * 7;
      bias_s[k2] = rpb[h * 169 + (ky + 3) * 13 + (kx + 3)];
    }
  }
  // ---- offset prefetch (global, consumed in phase 3) ----
  const float* offp = off_buf + (size_t)(b * 49) * 392 + h * 98;
  float2 offr[5];
#pragma unroll
  for (int p = 0; p < 5; ++p) {
    if (p < 4 || tid < 353) {  // 2401 = 4*512 + 353
      int e = tid + p * 512;
      unsigned int nu = (unsigned)e / 49u;
      int k2 = e - (int)nu * 49;
      offr[p] = *(const float2*)(offp + (size_t)nu * 392 + k2 * 2);
    }
  }
  __syncthreads();

  // ---- phase 2: S0 = q @ k^T via MFMA (8 waves x 16x32 quadrants) ----
  {
    const int lane = tid & 63;
    const int wv8 = tid >> 6;  // 0..7
    const int wrow = (wv8 >> 1) * 16;
    const int wcol = (wv8 & 1) * 32;
    const int lr = lane & 15;
    const int lg = lane >> 4;
    short8 af = *(const short8*)&qbs[(wrow + lr) * 40 + lg * 8];
    floatx4 z = {0.f, 0.f, 0.f, 0.f};
#pragma unroll
    for (int j = 0; j < 2; ++j) {
      short8 bf = *(const short8*)&kbs[(wcol + j * 16 + lr) * 40 + lg * 8];
      floatx4 c = __builtin_amdgcn_mfma_f32_16x16x32_bf16(af, bf, z, 0, 0, 0);
#pragma unroll
      for (int reg = 0; reg < 4; ++reg) {
        int grow = wrow + lg * 4 + reg;
        int gcol = wcol + j * 16 + lr;
        if (grow < 49 && gcol < 49) S0h[grow * 52 + gcol] = __float2half(c[reg]);
      }
    }
  }
  __syncthreads();  // all q/k reads done -> A2 region reusable

  // ---- zero A2 ----
  for (int i = tid; i < 637; i += 512)
    ((float4*)A2)[i] = make_float4(0.f, 0.f, 0.f, 0.f);
  __syncthreads();

  // ---- phase 3: scores + exp + unnormalized scatter ----
#pragma unroll
  for (int p = 0; p < 5; ++p) {
    if (p < 4 || tid < 353) {
      int e = tid + p * 512;
      unsigned int nu = (unsigned)e / 49u;
      int n = (int)nu;
      int k2 = e - n * 49;
      int iy = (int)(nu / 7u), ix = n - iy * 7;
      unsigned int ku = (unsigned)k2;
      int ky = (int)(ku / 7u), kx = k2 - ky * 7;
      float py = fminf(fmaxf((float)(iy + ky - 3) + offr[p].x, 0.f), 6.f);
      float px = fminf(fmaxf((float)(ix + kx - 3) + offr[p].y, 0.f), 6.f);
      float y0f = floorf(py), x0f = floorf(px);
      float wy = py - y0f, wx = px - x0f;
      int y0 = (int)y0f, x0 = (int)x0f;
      int y1 = min(y0 + 1, 6), x1 = min(x0 + 1, 6);
      const __half* srow = &S0h[n * 52];
      float* arow = A2 + n * 52;
      int i00 = y0 * 7 + x0, i01 = y0 * 7 + x1;
      int i10 = y1 * 7 + x0, i11 = y1 * 7 + x1;
      float w00 = (1.f - wy) * (1.f - wx);
      float w01 = (1.f - wy) * wx;
      float w10 = wy * (1.f - wx);
      float w11 = wy * wx;
      float s = w00 * __half2float(srow[i00]) + w01 * __half2float(srow[i01]) +
                w10 * __half2float(srow[i10]) + w11 * __half2float(srow[i11]) +
                bias_s[k2];
      float pe = __expf(s);  // no max-sub: scores ~N(0,1), exp-safe
      atomicAdd(arow + i00, pe * w00);
      atomicAdd(arow + i01, pe * w01);
      atomicAdd(arow + i10, pe * w10);
      atomicAdd(arow + i11, pe * w11);
    }
  }
  __syncthreads();

  // ---- phase 4: out = (A2 @ v) / rowsum(A2) ----
  {
    const int tx = tid & 15;   // d-pair
    const int ty = tid >> 4;   // 0..31
    int nr[2] = {ty, min(ty + 32, 48)};  // dup row-48 writes are identical
    float o0[2] = {0.f, 0.f}, o1[2] = {0.f, 0.f}, rs[2] = {0.f, 0.f};
#pragma unroll
    for (int m = 0; m < 48; m += 4) {
      float2 vf[4];
#pragma unroll
      for (int u = 0; u < 4; ++u)
        vf[u] = __half22float2(*(const __half2*)&vh[(m + u) * 36 + tx * 2]);
#pragma unroll
      for (int i = 0; i < 2; ++i) {
        float4 a = *(const float4*)&A2[nr[i] * 52 + m];
        o0[i] = fmaf(a.x, vf[0].x, o0[i]);
        o1[i] = fmaf(a.x, vf[0].y, o1[i]);
        o0[i] = fmaf(a.y, vf[1].x, o0[i]);
        o1[i] = fmaf(a.y, vf[1].y, o1[i]);
        o0[i] = fmaf(a.z, vf[2].x, o0[i]);
        o1[i] = fmaf(a.z, vf[2].y, o1[i]);
        o0[i] = fmaf(a.w, vf[3].x, o0[i]);
        o1[i] = fmaf(a.w, vf[3].y, o1[i]);
        rs[i] += (a.x + a.y) + (a.z + a.w);
      }
    }
    float2 v48 = __half22float2(*(const __half2*)&vh[48 * 36 + tx * 2]);
#pragma unroll
    for (int i = 0; i < 2; ++i) {
      float a = A2[nr[i] * 52 + 48];
      o0[i] = fmaf(a, v48.x, o0[i]);
      o1[i] = fmaf(a, v48.y, o1[i]);
      rs[i] += a;
      float inv = 1.f / rs[i];
      *(float2*)&attn_out[(size_t)(b * 49 + nr[i]) * 128 + h * 32 + tx * 2] =
          make_float2(o0[i] * inv, o1[i] * inv);
    }
  }
}

// ---------------------------------------------------------------------------
extern "C" void kernel_launch(void* const* d_in, const int* in_sizes, int n_in,
                              void* d_out, int out_size, void* d_ws,
                              size_t ws_size, hipStream_t stream) {
  const float* x = (const float*)d_in[0];
  const float* w_qkv = (const float*)d_in[1];
  const float* b_qkv = (const float*)d_in[2];
  const float* w_off = (const float*)d_in[3];
  const float* b_off = (const float*)d_in[4];
  const float* rpb = (const float*)d_in[5];
  const float* w_proj = (const float*)d_in[6];
  const float* b_proj = (const float*)d_in[7];
  float* out = (float*)d_out;

  float* ws = (float*)d_ws;
  float* qkv_buf = ws;                              // 12544*384
  float* off_buf = qkv_buf + (size_t)MROWS * 384;   // 12544*392
  float* attn_out = off_buf + (size_t)MROWS * 392;  // 12544*128

  dwa_gemm<0><<<dim3(196, 13), 256, 0, stream>>>(x, w_qkv, w_off, b_qkv, b_off,
                                                 qkv_buf, off_buf);
  dwa_attn<<<BATCH * HEADS, 512, 0, stream>>>(qkv_buf, off_buf, rpb, attn_out);
  dwa_gemm<1><<<dim3(196, 2), 256, 0, stream>>>(attn_out, w_proj, nullptr,
                                                b_proj, nullptr, out, nullptr);
}